// Round 3
// baseline (575.066 us; speedup 1.0000x reference)
//
#include <hip/hip_runtime.h>

// ---------------------------------------------------------------------------
// AttentionMulti: x[4,2048,1024] fp32 -> qkv -> 16-head attention (D=64,
// scale=0.5, key-mask) -> out proj.  Inputs/outputs fp32, mask int32.
// Internal compute in bf16 MFMA (threshold is 2% relative -> ample margin).
// Pipeline:
//   0. convert x fp32 -> xb bf16                              (ws)
//   1. transpose+convert w_qkv [1024][3072]f32 -> wqkvT bf16  (ws)
//   2. transpose+convert w_out [1024][1024]f32 -> woutT bf16  (ws)
//   3. gemm: qkv[8192][3072] = xb @ wqkvT^T + b_qkv  (bf16 out)
//   4. attention -> O[8192][1024] bf16
//   5. gemm: out = O @ woutT^T + b_out  (fp32 out -> d_out)
// ---------------------------------------------------------------------------

typedef __bf16 bf16;
typedef __attribute__((ext_vector_type(8))) __bf16 bf16x8;
typedef __attribute__((ext_vector_type(4))) float f32x4;

#define MFMA16(a, b, c) __builtin_amdgcn_mfma_f32_16x16x32_bf16(a, b, c, 0, 0, 0)

// ---------------------------------------------------------------------------
// Elementwise fp32 -> bf16 (4 elements/thread)
// ---------------------------------------------------------------------------
__global__ __launch_bounds__(256, 1) void cvt_f32_bf16(
    const float* __restrict__ in, bf16* __restrict__ out, int n4)
{
    int i = blockIdx.x * 256 + threadIdx.x;
    if (i >= n4) return;
    float4 v = *(const float4*)(in + (size_t)i * 4);
    union { ushort4 u; bf16 h[4]; } o;
    o.h[0] = (bf16)v.x; o.h[1] = (bf16)v.y; o.h[2] = (bf16)v.z; o.h[3] = (bf16)v.w;
    *(ushort4*)(out + (size_t)i * 4) = o.u;
}

// ---------------------------------------------------------------------------
// 64x64 tile transpose + fp32->bf16: out[c*R + r] = (bf16)in[r*C + c]
// ---------------------------------------------------------------------------
__global__ __launch_bounds__(256, 1) void transpose_f32_bf16(
    const float* __restrict__ in, bf16* __restrict__ out, int R, int C)
{
    __shared__ float s[64][65];
    const int t  = threadIdx.x;
    const int r0 = blockIdx.y * 64;
    const int c0 = blockIdx.x * 64;
    // read: 16 rows/pass x (16 lanes * float4)
    const int tr  = t >> 4;          // 0..15
    const int tc4 = (t & 15) * 4;    // 0..60
#pragma unroll
    for (int p = 0; p < 4; ++p) {
        int r = tr + p * 16;
        float4 v = *(const float4*)(in + (size_t)(r0 + r) * C + c0 + tc4);
        s[r][tc4 + 0] = v.x; s[r][tc4 + 1] = v.y;
        s[r][tc4 + 2] = v.z; s[r][tc4 + 3] = v.w;
    }
    __syncthreads();
    // write: 32 out-rows/pass x (8 lanes * 8 bf16)
    const int cw  = t >> 3;          // 0..31
    const int rw8 = (t & 7) * 8;     // 0..56
#pragma unroll
    for (int p = 0; p < 2; ++p) {
        int c = cw + p * 32;
        union { uint4 v; bf16 h[8]; } u;
#pragma unroll
        for (int j = 0; j < 8; ++j) u.h[j] = (bf16)s[rw8 + j][c];
        *(uint4*)(out + (size_t)(c0 + c) * R + r0 + rw8) = u.v;
    }
}

// ---------------------------------------------------------------------------
// C[M][N] = A[M][K] @ Bt[N][K]^T + bias[N]   (m97-style 128x128 tile, BK=32)
// A,Bt bf16; bias fp32; OutT = bf16 or float.
// ---------------------------------------------------------------------------
template <typename OutT>
__global__ __launch_bounds__(256, 1) void gemm_bias_kernel(
    const bf16* __restrict__ A, const bf16* __restrict__ Bt,
    const float* __restrict__ bias, OutT* __restrict__ C,
    int M, int N, int K)
{
    __shared__ __align__(16) bf16 As[128 * 32];
    __shared__ __align__(16) bf16 Bs[128 * 32];
    const int t    = threadIdx.x;
    const int lane = t & 63;
    const int wave = t >> 6;
    const int l15  = lane & 15;
    const int g    = lane >> 4;
    const int m0   = blockIdx.y * 128;
    const int n0   = blockIdx.x * 128;
    const int wr   = (wave >> 1) * 64;
    const int wc   = (wave & 1) * 64;

    const f32x4 z = {0.f, 0.f, 0.f, 0.f};
    f32x4 acc[4][4];
#pragma unroll
    for (int i = 0; i < 4; ++i)
#pragma unroll
        for (int j = 0; j < 4; ++j) acc[i][j] = z;

    const int e0 = t * 8;  // 8 bf16 = 16 B per lane per staging round

    for (int k0 = 0; k0 < K; k0 += 32) {
        __syncthreads();
#pragma unroll
        for (int rnd = 0; rnd < 2; ++rnd) {
            int e   = e0 + rnd * 2048;
            int row = e >> 5;
            int col = e & 31;
            __builtin_amdgcn_global_load_lds(
                (const __attribute__((address_space(1))) void*)(A + (size_t)(m0 + row) * K + k0 + col),
                (__attribute__((address_space(3))) void*)(As + e), 16, 0, 0);
            __builtin_amdgcn_global_load_lds(
                (const __attribute__((address_space(1))) void*)(Bt + (size_t)(n0 + row) * K + k0 + col),
                (__attribute__((address_space(3))) void*)(Bs + e), 16, 0, 0);
        }
        asm volatile("s_waitcnt vmcnt(0)" ::: "memory");
        __syncthreads();

        bf16x8 a[4], b[4];
#pragma unroll
        for (int i = 0; i < 4; ++i)
            a[i] = *(const bf16x8*)(As + (wr + i * 16 + l15) * 32 + g * 8);
#pragma unroll
        for (int j = 0; j < 4; ++j)
            b[j] = *(const bf16x8*)(Bs + (wc + j * 16 + l15) * 32 + g * 8);
#pragma unroll
        for (int i = 0; i < 4; ++i)
#pragma unroll
            for (int j = 0; j < 4; ++j)
                acc[i][j] = MFMA16(a[i], b[j], acc[i][j]);
    }

#pragma unroll
    for (int i = 0; i < 4; ++i) {
#pragma unroll
        for (int j = 0; j < 4; ++j) {
#pragma unroll
            for (int r = 0; r < 4; ++r) {
                int row = m0 + wr + i * 16 + g * 4 + r;
                int col = n0 + wc + j * 16 + l15;
                float v = acc[i][j][r] + bias[col];
                C[(size_t)row * N + col] = (OutT)v;
            }
        }
    }
}

// ---------------------------------------------------------------------------
// Attention: qkv [8192][3072] bf16 (q|k|v, head h at cols h*64..h*64+63)
//   -> O [8192][1024] bf16.  One block = (b, h, 64 q-rows); wave = 16 q-rows.
//   Un-shifted exp2 softmax (scores bounded; clamp+guard = NaN-proof),
//   denominator via ones-MFMA; P roundtrip via LDS + __syncthreads.
// ---------------------------------------------------------------------------
__global__ __launch_bounds__(256, 1) void attn_kernel(
    const bf16* __restrict__ qkv, const int* __restrict__ mask,
    bf16* __restrict__ O)
{
    __shared__ int mask_s[2048];
    __shared__ __align__(16) bf16 Vt[64 * 40];      // [d][key], stride 40 (80 B, 16B-aligned)
    __shared__ __align__(16) bf16 Ps[4][16 * 32];   // per-wave P roundtrip

    const int t    = threadIdx.x;
    const int lane = t & 63;
    const int wave = t >> 6;
    const int l15  = lane & 15;
    const int g    = lane >> 4;

    const int bid = blockIdx.x;       // 0..2047
    const int qt  = bid & 31;         // q-tile (64 rows)
    const int bh  = bid >> 5;
    const int h   = bh & 15;
    const int b   = bh >> 4;
    const int q0  = qt * 64 + wave * 16;

    for (int i = t; i < 2048; i += 256) mask_s[i] = mask[b * 2048 + i];

    const size_t RS = 3072;
    const bf16* qptr = qkv + (size_t)(b * 2048 + q0 + l15) * RS + h * 64 + g * 8;
    const bf16x8 aQ0 = *(const bf16x8*)(qptr);
    const bf16x8 aQ1 = *(const bf16x8*)(qptr + 32);

    const bf16* kbase = qkv + (size_t)(b * 2048) * RS + 1024 + h * 64;
    const bf16* vbase = qkv + (size_t)(b * 2048) * RS + 2048 + h * 64;

    const f32x4 z = {0.f, 0.f, 0.f, 0.f};
    f32x4 o0 = z, o1 = z, o2 = z, o3 = z, lacc = z;

    bf16x8 onesf;
#pragma unroll
    for (int j = 0; j < 8; ++j) onesf[j] = (bf16)1.0f;

    const int vkey = t & 31;          // V staging: key within chunk
    const int vd0  = (t >> 5) * 8;    // V staging: d range

    const float SC = 0.72134752f;     // 0.5 * log2(e)

    for (int kc = 0; kc < 2048; kc += 32) {
        __syncthreads();              // prior chunk's Vt/Ps reads complete
        {
            union { uint4 v; bf16 h8[8]; } u;
            u.v = *(const uint4*)(vbase + (size_t)(kc + vkey) * RS + vd0);
#pragma unroll
            for (int j = 0; j < 8; ++j) Vt[(vd0 + j) * 40 + vkey] = u.h8[j];
        }
        __syncthreads();              // Vt (and iter-0 mask_s) ready

        // ---- S = 0.5 * Q K^T  (16 q x 32 keys) ----
        const bf16* kp0 = kbase + (size_t)(kc + l15) * RS + g * 8;
        const bf16* kp1 = kp0 + 16 * RS;
        bf16x8 bk00 = *(const bf16x8*)(kp0);
        bf16x8 bk01 = *(const bf16x8*)(kp0 + 32);
        bf16x8 bk10 = *(const bf16x8*)(kp1);
        bf16x8 bk11 = *(const bf16x8*)(kp1 + 32);
        f32x4 S0 = z, S1 = z;
        S0 = MFMA16(aQ0, bk00, S0);
        S0 = MFMA16(aQ1, bk01, S0);
        S1 = MFMA16(aQ0, bk10, S1);
        S1 = MFMA16(aQ1, bk11, S1);

        // ---- mask + exp2 (clamped; legit |arg| <= ~26) -> P (bf16) to LDS ----
        const bool mk0 = mask_s[kc + l15] != 0;
        const bool mk1 = mask_s[kc + 16 + l15] != 0;
#pragma unroll
        for (int r = 0; r < 4; ++r) {
            float p0 = mk0 ? exp2f(fminf(S0[r] * SC, 126.0f)) : 0.f;
            float p1 = mk1 ? exp2f(fminf(S1[r] * SC, 126.0f)) : 0.f;
            Ps[wave][(g * 4 + r) * 32 + l15]      = (bf16)p0;
            Ps[wave][(g * 4 + r) * 32 + 16 + l15] = (bf16)p1;
        }
        __syncthreads();              // P committed to LDS (real fence)

        // ---- P (A-layout) and PV + row-sum MFMAs ----
        const bf16x8 aP = *(const bf16x8*)(&Ps[wave][l15 * 32 + g * 8]);
        lacc = MFMA16(aP, onesf, lacc);
        {
            bf16x8 bv0 = *(const bf16x8*)(&Vt[(0 * 16 + l15) * 40 + g * 8]);
            bf16x8 bv1 = *(const bf16x8*)(&Vt[(1 * 16 + l15) * 40 + g * 8]);
            bf16x8 bv2 = *(const bf16x8*)(&Vt[(2 * 16 + l15) * 40 + g * 8]);
            bf16x8 bv3 = *(const bf16x8*)(&Vt[(3 * 16 + l15) * 40 + g * 8]);
            o0 = MFMA16(aP, bv0, o0);
            o1 = MFMA16(aP, bv1, o1);
            o2 = MFMA16(aP, bv2, o2);
            o3 = MFMA16(aP, bv3, o3);
        }
    }

    // ---- normalize + store (guarded: no 0/0 or inf/inf possible) ----
    float inv[4];
#pragma unroll
    for (int r = 0; r < 4; ++r) inv[r] = 1.0f / fmaxf(lacc[r], 1e-35f);

    const f32x4 oo[4] = {o0, o1, o2, o3};
#pragma unroll
    for (int nt = 0; nt < 4; ++nt) {
#pragma unroll
        for (int r = 0; r < 4; ++r) {
            int row = q0 + g * 4 + r;
            int d   = nt * 16 + l15;
            O[(size_t)(b * 2048 + row) * 1024 + h * 64 + d] = (bf16)(oo[nt][r] * inv[r]);
        }
    }
}

// ---------------------------------------------------------------------------
extern "C" void kernel_launch(void* const* d_in, const int* in_sizes, int n_in,
                              void* d_out, int out_size, void* d_ws, size_t ws_size,
                              hipStream_t stream)
{
    const float* x     = (const float*)d_in[0];
    const int*   mask  = (const int*)d_in[1];
    const float* w_qkv = (const float*)d_in[2];
    const float* b_qkv = (const float*)d_in[3];
    const float* w_out = (const float*)d_in[4];
    const float* b_out = (const float*)d_in[5];
    float* out = (float*)d_out;

    char* ws = (char*)d_ws;
    bf16* qkvb  = (bf16*)(ws);                 // 48 MiB: [8192][3072]
    bf16* Obuf  = (bf16*)(ws + 50331648);      // 16 MiB: [8192][1024]
    bf16* xb    = (bf16*)(ws + 67108864);      // 16 MiB: [8192][1024]
    bf16* wqkvT = (bf16*)(ws + 83886080);      //  6 MiB: [3072][1024]
    bf16* woutT = (bf16*)(ws + 90177536);      //  2 MiB: [1024][1024]

    cvt_f32_bf16<<<dim3(8192), 256, 0, stream>>>(x, xb, 2097152);
    transpose_f32_bf16<<<dim3(48, 16), 256, 0, stream>>>(w_qkv, wqkvT, 1024, 3072);
    transpose_f32_bf16<<<dim3(16, 16), 256, 0, stream>>>(w_out, woutT, 1024, 1024);
    gemm_bias_kernel<bf16><<<dim3(24, 64), 256, 0, stream>>>(xb, wqkvT, b_qkv, qkvb, 8192, 3072, 1024);
    attn_kernel<<<dim3(2048), 256, 0, stream>>>(qkvb, mask, Obuf);
    gemm_bias_kernel<float><<<dim3(8, 64), 256, 0, stream>>>(Obuf, woutT, b_out, out, 8192, 1024, 1024);
}

// Round 4
// 498.649 us; speedup vs baseline: 1.1532x; 1.1532x over previous
//
#include <hip/hip_runtime.h>

// ---------------------------------------------------------------------------
// AttentionMulti: x[4,2048,1024] fp32 -> qkv -> 16-head attention (D=64,
// scale=0.5, key-mask) -> out proj.  Inputs/outputs fp32, mask int32.
// Internal compute in bf16 MFMA.
// ---------------------------------------------------------------------------

typedef __bf16 bf16;
typedef __attribute__((ext_vector_type(8))) __bf16 bf16x8;
typedef __attribute__((ext_vector_type(4))) float f32x4;

#define MFMA16(a, b, c) __builtin_amdgcn_mfma_f32_16x16x32_bf16(a, b, c, 0, 0, 0)

// ---------------------------------------------------------------------------
// Elementwise fp32 -> bf16 (4 elements/thread)
// ---------------------------------------------------------------------------
__global__ __launch_bounds__(256, 1) void cvt_f32_bf16(
    const float* __restrict__ in, bf16* __restrict__ out, int n4)
{
    int i = blockIdx.x * 256 + threadIdx.x;
    if (i >= n4) return;
    float4 v = *(const float4*)(in + (size_t)i * 4);
    union { ushort4 u; bf16 h[4]; } o;
    o.h[0] = (bf16)v.x; o.h[1] = (bf16)v.y; o.h[2] = (bf16)v.z; o.h[3] = (bf16)v.w;
    *(ushort4*)(out + (size_t)i * 4) = o.u;
}

// ---------------------------------------------------------------------------
// 64x64 tile transpose + fp32->bf16: out[c*R + r] = (bf16)in[r*C + c]
// ---------------------------------------------------------------------------
__global__ __launch_bounds__(256, 1) void transpose_f32_bf16(
    const float* __restrict__ in, bf16* __restrict__ out, int R, int C)
{
    __shared__ float s[64][65];
    const int t  = threadIdx.x;
    const int r0 = blockIdx.y * 64;
    const int c0 = blockIdx.x * 64;
    const int tr  = t >> 4;          // 0..15
    const int tc4 = (t & 15) * 4;    // 0..60
#pragma unroll
    for (int p = 0; p < 4; ++p) {
        int r = tr + p * 16;
        float4 v = *(const float4*)(in + (size_t)(r0 + r) * C + c0 + tc4);
        s[r][tc4 + 0] = v.x; s[r][tc4 + 1] = v.y;
        s[r][tc4 + 2] = v.z; s[r][tc4 + 3] = v.w;
    }
    __syncthreads();
    const int cw  = t >> 3;          // 0..31
    const int rw8 = (t & 7) * 8;     // 0..56
#pragma unroll
    for (int p = 0; p < 2; ++p) {
        int c = cw + p * 32;
        union { uint4 v; bf16 h[8]; } u;
#pragma unroll
        for (int j = 0; j < 8; ++j) u.h[j] = (bf16)s[rw8 + j][c];
        *(uint4*)(out + (size_t)(c0 + c) * R + r0 + rw8) = u.v;
    }
}

// ---------------------------------------------------------------------------
// C[M][N] = A[M][K] @ Bt[N][K]^T + bias[N]   (m97-style 128x128 tile, BK=32)
// ---------------------------------------------------------------------------
template <typename OutT>
__global__ __launch_bounds__(256, 1) void gemm_bias_kernel(
    const bf16* __restrict__ A, const bf16* __restrict__ Bt,
    const float* __restrict__ bias, OutT* __restrict__ C,
    int M, int N, int K)
{
    __shared__ __align__(16) bf16 As[128 * 32];
    __shared__ __align__(16) bf16 Bs[128 * 32];
    const int t    = threadIdx.x;
    const int lane = t & 63;
    const int wave = t >> 6;
    const int l15  = lane & 15;
    const int g    = lane >> 4;
    const int m0   = blockIdx.y * 128;
    const int n0   = blockIdx.x * 128;
    const int wr   = (wave >> 1) * 64;
    const int wc   = (wave & 1) * 64;

    const f32x4 z = {0.f, 0.f, 0.f, 0.f};
    f32x4 acc[4][4];
#pragma unroll
    for (int i = 0; i < 4; ++i)
#pragma unroll
        for (int j = 0; j < 4; ++j) acc[i][j] = z;

    const int e0 = t * 8;

    for (int k0 = 0; k0 < K; k0 += 32) {
        __syncthreads();
#pragma unroll
        for (int rnd = 0; rnd < 2; ++rnd) {
            int e   = e0 + rnd * 2048;
            int row = e >> 5;
            int col = e & 31;
            __builtin_amdgcn_global_load_lds(
                (const __attribute__((address_space(1))) void*)(A + (size_t)(m0 + row) * K + k0 + col),
                (__attribute__((address_space(3))) void*)(As + e), 16, 0, 0);
            __builtin_amdgcn_global_load_lds(
                (const __attribute__((address_space(1))) void*)(Bt + (size_t)(n0 + row) * K + k0 + col),
                (__attribute__((address_space(3))) void*)(Bs + e), 16, 0, 0);
        }
        asm volatile("s_waitcnt vmcnt(0)" ::: "memory");
        __syncthreads();

        bf16x8 a[4], b[4];
#pragma unroll
        for (int i = 0; i < 4; ++i)
            a[i] = *(const bf16x8*)(As + (wr + i * 16 + l15) * 32 + g * 8);
#pragma unroll
        for (int j = 0; j < 4; ++j)
            b[j] = *(const bf16x8*)(Bs + (wc + j * 16 + l15) * 32 + g * 8);
#pragma unroll
        for (int i = 0; i < 4; ++i)
#pragma unroll
            for (int j = 0; j < 4; ++j)
                acc[i][j] = MFMA16(a[i], b[j], acc[i][j]);
    }

#pragma unroll
    for (int i = 0; i < 4; ++i) {
#pragma unroll
        for (int j = 0; j < 4; ++j) {
#pragma unroll
            for (int r = 0; r < 4; ++r) {
                int row = m0 + wr + i * 16 + g * 4 + r;
                int col = n0 + wc + j * 16 + l15;
                float v = acc[i][j][r] + bias[col];
                C[(size_t)row * N + col] = (OutT)v;
            }
        }
    }
}

// ---------------------------------------------------------------------------
// Attention v2: 64-key chunks, double-buffered V-transpose in LDS, per-wave
// P roundtrip synced by lgkmcnt only, ONE __syncthreads per chunk.
//   block = (b, h, 64 q-rows); wave = 16 q-rows; 32 chunk iterations.
//   Vt rows stride 72 (144 B: 16B-aligned, bank-shift 4/row -> conflict-free
//   stage writes); Ps rows stride 72.  Mask pre-baked as float bias (0/-1e30)
//   folded into the exp2 argument FMA.  Denominator via ones-MFMA.
// ---------------------------------------------------------------------------
__global__ __launch_bounds__(256, 4) void attn_kernel(
    const bf16* __restrict__ qkv, const int* __restrict__ mask,
    bf16* __restrict__ O)
{
    __shared__ float maskb[2048];                    // 8 KB: 0 or -1e30
    __shared__ __align__(16) bf16 Vt[2][64 * 72];    // 2 x 9216 B
    __shared__ __align__(16) bf16 Ps[4][16 * 72];    // 4 x 2304 B

    const int t    = threadIdx.x;
    const int lane = t & 63;
    const int wave = t >> 6;
    const int l15  = lane & 15;
    const int g    = lane >> 4;

    const int bid = blockIdx.x;       // 0..2047
    const int qt  = bid & 31;
    const int bh  = bid >> 5;
    const int h   = bh & 15;
    const int b   = bh >> 4;
    const int q0  = qt * 64 + wave * 16;

    for (int i = t; i < 2048; i += 256)
        maskb[i] = mask[b * 2048 + i] ? 0.0f : -1e30f;

    const size_t RS = 3072;
    const bf16* qptr = qkv + (size_t)(b * 2048 + q0 + l15) * RS + h * 64 + g * 8;
    const bf16x8 aQ0 = *(const bf16x8*)(qptr);
    const bf16x8 aQ1 = *(const bf16x8*)(qptr + 32);

    const bf16* kbase = qkv + (size_t)(b * 2048) * RS + 1024 + h * 64;
    const bf16* vbase = qkv + (size_t)(b * 2048) * RS + 2048 + h * 64;

    const f32x4 z = {0.f, 0.f, 0.f, 0.f};
    f32x4 o0 = z, o1 = z, o2 = z, o3 = z, lacc = z;

    bf16x8 onesf;
#pragma unroll
    for (int j = 0; j < 8; ++j) onesf[j] = (bf16)1.0f;

    // V staging: thread t covers key (t&63), d-range (t>>6)*16 .. +15
    const int vrow = t & 63;
    const int vd   = (t >> 6) * 16;
    const bf16* vp0 = vbase + (size_t)vrow * RS + vd;

    const float SC = 0.72134752f;     // 0.5 * log2(e)

    // ---- stage chunk 0 ----
    {
        union { uint4 u4[2]; bf16 hh[16]; } uv;
        uv.u4[0] = *(const uint4*)(vp0);
        uv.u4[1] = *(const uint4*)(vp0 + 8);
#pragma unroll
        for (int j = 0; j < 16; ++j) Vt[0][(vd + j) * 72 + vrow] = uv.hh[j];
    }
    __syncthreads();

    for (int i = 0; i < 32; ++i) {
        const int kc  = i * 64;
        const int buf = i & 1;

        // ---- prefetch-stage next V chunk into the other buffer ----
        if (i + 1 < 32) {
            union { uint4 u4[2]; bf16 hh[16]; } uv;
            const bf16* vp = vp0 + (size_t)(kc + 64) * RS;
            uv.u4[0] = *(const uint4*)(vp);
            uv.u4[1] = *(const uint4*)(vp + 8);
#pragma unroll
            for (int j = 0; j < 16; ++j) Vt[buf ^ 1][(vd + j) * 72 + vrow] = uv.hh[j];
        }

        // ---- S = 0.5 * Q K^T  (16 q x 64 keys, 4 key-tiles) ----
        f32x4 S[4];
#pragma unroll
        for (int kt = 0; kt < 4; ++kt) {
            const bf16* kp = kbase + (size_t)(kc + kt * 16 + l15) * RS + g * 8;
            bf16x8 bk0 = *(const bf16x8*)(kp);
            bf16x8 bk1 = *(const bf16x8*)(kp + 32);
            S[kt] = MFMA16(aQ0, bk0, z);
            S[kt] = MFMA16(aQ1, bk1, S[kt]);
        }

        // ---- P = exp2(S*SC + maskbias)  -> per-wave LDS (A-layout src) ----
#pragma unroll
        for (int kt = 0; kt < 4; ++kt) {
            const float mb = maskb[kc + kt * 16 + l15];
#pragma unroll
            for (int r = 0; r < 4; ++r) {
                float e = fminf(fmaf(S[kt][r], SC, mb), 126.0f);
                Ps[wave][(g * 4 + r) * 72 + kt * 16 + l15] =
                    (bf16)__builtin_amdgcn_exp2f(e);
            }
        }
        asm volatile("s_waitcnt lgkmcnt(0)" ::: "memory");  // wave-local fence

        // ---- P (A-layout, K=64 as two frags) ----
        const bf16x8 aP0 = *(const bf16x8*)(&Ps[wave][l15 * 72 + g * 8]);
        const bf16x8 aP1 = *(const bf16x8*)(&Ps[wave][l15 * 72 + 32 + g * 8]);

        lacc = MFMA16(aP0, onesf, lacc);
        lacc = MFMA16(aP1, onesf, lacc);

        // ---- PV: 4 d-tiles x 2 key-frags ----
#pragma unroll
        for (int dt = 0; dt < 4; ++dt) {
            bf16x8 bv0 = *(const bf16x8*)(&Vt[buf][(dt * 16 + l15) * 72 + g * 8]);
            bf16x8 bv1 = *(const bf16x8*)(&Vt[buf][(dt * 16 + l15) * 72 + 32 + g * 8]);
            f32x4* op = (dt == 0) ? &o0 : (dt == 1) ? &o1 : (dt == 2) ? &o2 : &o3;
            *op = MFMA16(aP0, bv0, *op);
            *op = MFMA16(aP1, bv1, *op);
        }

        __syncthreads();   // Vt[buf^1] staged for all; Vt[buf] reads done
    }

    // ---- normalize + store ----
    float inv[4];
#pragma unroll
    for (int r = 0; r < 4; ++r) inv[r] = 1.0f / fmaxf(lacc[r], 1e-35f);

    const f32x4 oo[4] = {o0, o1, o2, o3};
#pragma unroll
    for (int nt = 0; nt < 4; ++nt) {
#pragma unroll
        for (int r = 0; r < 4; ++r) {
            int row = q0 + g * 4 + r;
            int d   = nt * 16 + l15;
            O[(size_t)(b * 2048 + row) * 1024 + h * 64 + d] = (bf16)(oo[nt][r] * inv[r]);
        }
    }
}

// ---------------------------------------------------------------------------
extern "C" void kernel_launch(void* const* d_in, const int* in_sizes, int n_in,
                              void* d_out, int out_size, void* d_ws, size_t ws_size,
                              hipStream_t stream)
{
    const float* x     = (const float*)d_in[0];
    const int*   mask  = (const int*)d_in[1];
    const float* w_qkv = (const float*)d_in[2];
    const float* b_qkv = (const float*)d_in[3];
    const float* w_out = (const float*)d_in[4];
    const float* b_out = (const float*)d_in[5];
    float* out = (float*)d_out;

    char* ws = (char*)d_ws;
    bf16* qkvb  = (bf16*)(ws);                 // 48 MiB: [8192][3072]
    bf16* Obuf  = (bf16*)(ws + 50331648);      // 16 MiB: [8192][1024]
    bf16* xb    = (bf16*)(ws + 67108864);      // 16 MiB: [8192][1024]
    bf16* wqkvT = (bf16*)(ws + 83886080);      //  6 MiB: [3072][1024]
    bf16* woutT = (bf16*)(ws + 90177536);      //  2 MiB: [1024][1024]

    cvt_f32_bf16<<<dim3(8192), 256, 0, stream>>>(x, xb, 2097152);
    transpose_f32_bf16<<<dim3(48, 16), 256, 0, stream>>>(w_qkv, wqkvT, 1024, 3072);
    transpose_f32_bf16<<<dim3(16, 16), 256, 0, stream>>>(w_out, woutT, 1024, 1024);
    gemm_bias_kernel<bf16><<<dim3(24, 64), 256, 0, stream>>>(xb, wqkvT, b_qkv, qkvb, 8192, 3072, 1024);
    attn_kernel<<<dim3(2048), 256, 0, stream>>>(qkvb, mask, Obuf);
    gemm_bias_kernel<float><<<dim3(8, 64), 256, 0, stream>>>(Obuf, woutT, b_out, out, 8192, 1024, 1024);
}

// Round 5
// 345.602 us; speedup vs baseline: 1.6640x; 1.4428x over previous
//
#include <hip/hip_runtime.h>

// ---------------------------------------------------------------------------
// AttentionMulti: x[4,2048,1024] fp32 -> qkv -> 16-head attention (D=64,
// scale=0.5, key-mask) -> out proj.  Inputs/outputs fp32, mask int32.
// Internal compute in bf16 MFMA.
// ---------------------------------------------------------------------------

typedef __bf16 bf16;
typedef __attribute__((ext_vector_type(8))) __bf16 bf16x8;
typedef __attribute__((ext_vector_type(4))) float f32x4;

#define MFMA16(a, b, c) __builtin_amdgcn_mfma_f32_16x16x32_bf16(a, b, c, 0, 0, 0)

// ---------------------------------------------------------------------------
__global__ __launch_bounds__(256, 1) void cvt_f32_bf16(
    const float* __restrict__ in, bf16* __restrict__ out, int n4)
{
    int i = blockIdx.x * 256 + threadIdx.x;
    if (i >= n4) return;
    float4 v = *(const float4*)(in + (size_t)i * 4);
    union { ushort4 u; bf16 h[4]; } o;
    o.h[0] = (bf16)v.x; o.h[1] = (bf16)v.y; o.h[2] = (bf16)v.z; o.h[3] = (bf16)v.w;
    *(ushort4*)(out + (size_t)i * 4) = o.u;
}

// ---------------------------------------------------------------------------
__global__ __launch_bounds__(256, 1) void transpose_f32_bf16(
    const float* __restrict__ in, bf16* __restrict__ out, int R, int C)
{
    __shared__ float s[64][65];
    const int t  = threadIdx.x;
    const int r0 = blockIdx.y * 64;
    const int c0 = blockIdx.x * 64;
    const int tr  = t >> 4;
    const int tc4 = (t & 15) * 4;
#pragma unroll
    for (int p = 0; p < 4; ++p) {
        int r = tr + p * 16;
        float4 v = *(const float4*)(in + (size_t)(r0 + r) * C + c0 + tc4);
        s[r][tc4 + 0] = v.x; s[r][tc4 + 1] = v.y;
        s[r][tc4 + 2] = v.z; s[r][tc4 + 3] = v.w;
    }
    __syncthreads();
    const int cw  = t >> 3;
    const int rw8 = (t & 7) * 8;
#pragma unroll
    for (int p = 0; p < 2; ++p) {
        int c = cw + p * 32;
        union { uint4 v; bf16 h[8]; } u;
#pragma unroll
        for (int j = 0; j < 8; ++j) u.h[j] = (bf16)s[rw8 + j][c];
        *(uint4*)(out + (size_t)(c0 + c) * R + r0 + rw8) = u.v;
    }
}

// ---------------------------------------------------------------------------
// C[M][N] = A[M][K] @ Bt[N][K]^T + bias[N]   (m97-style 128x128 tile, BK=32)
// ---------------------------------------------------------------------------
template <typename OutT>
__global__ __launch_bounds__(256, 1) void gemm_bias_kernel(
    const bf16* __restrict__ A, const bf16* __restrict__ Bt,
    const float* __restrict__ bias, OutT* __restrict__ C,
    int M, int N, int K)
{
    __shared__ __align__(16) bf16 As[128 * 32];
    __shared__ __align__(16) bf16 Bs[128 * 32];
    const int t    = threadIdx.x;
    const int lane = t & 63;
    const int wave = t >> 6;
    const int l15  = lane & 15;
    const int g    = lane >> 4;
    const int m0   = blockIdx.y * 128;
    const int n0   = blockIdx.x * 128;
    const int wr   = (wave >> 1) * 64;
    const int wc   = (wave & 1) * 64;

    const f32x4 z = {0.f, 0.f, 0.f, 0.f};
    f32x4 acc[4][4];
#pragma unroll
    for (int i = 0; i < 4; ++i)
#pragma unroll
        for (int j = 0; j < 4; ++j) acc[i][j] = z;

    const int e0 = t * 8;

    for (int k0 = 0; k0 < K; k0 += 32) {
        __syncthreads();
#pragma unroll
        for (int rnd = 0; rnd < 2; ++rnd) {
            int e   = e0 + rnd * 2048;
            int row = e >> 5;
            int col = e & 31;
            __builtin_amdgcn_global_load_lds(
                (const __attribute__((address_space(1))) void*)(A + (size_t)(m0 + row) * K + k0 + col),
                (__attribute__((address_space(3))) void*)(As + e), 16, 0, 0);
            __builtin_amdgcn_global_load_lds(
                (const __attribute__((address_space(1))) void*)(Bt + (size_t)(n0 + row) * K + k0 + col),
                (__attribute__((address_space(3))) void*)(Bs + e), 16, 0, 0);
        }
        asm volatile("s_waitcnt vmcnt(0)" ::: "memory");
        __syncthreads();

        bf16x8 a[4], b[4];
#pragma unroll
        for (int i = 0; i < 4; ++i)
            a[i] = *(const bf16x8*)(As + (wr + i * 16 + l15) * 32 + g * 8);
#pragma unroll
        for (int j = 0; j < 4; ++j)
            b[j] = *(const bf16x8*)(Bs + (wc + j * 16 + l15) * 32 + g * 8);
#pragma unroll
        for (int i = 0; i < 4; ++i)
#pragma unroll
            for (int j = 0; j < 4; ++j)
                acc[i][j] = MFMA16(a[i], b[j], acc[i][j]);
    }

#pragma unroll
    for (int i = 0; i < 4; ++i) {
#pragma unroll
        for (int j = 0; j < 4; ++j) {
#pragma unroll
            for (int r = 0; r < 4; ++r) {
                int row = m0 + wr + i * 16 + g * 4 + r;
                int col = n0 + wc + j * 16 + l15;
                float v = acc[i][j][r] + bias[col];
                C[(size_t)row * N + col] = (OutT)v;
            }
        }
    }
}

// ---------------------------------------------------------------------------
// Attention v3:
//  - K staged ONCE per block into LDS (was 4x wave-redundant global loads),
//    double-buffered, XOR-swizzled (dblk ^= key&7) -> bank-balanced b128
//    writes AND reads with no padding (16 KB).
//  - Global K/V prefetch for chunk i+1 issued right after the compute
//    barrier, consumed (ds_write / reg save) at loop tail -> latency covered
//    by compute; nothing global on the QK chain.
//  - Mask out of the exp chain: V rows zeroed at staging; denominator via
//    mask-indicator B-fragment MFMA (replaces ones-MFMA).  exp = mul+exp+cvt.
//  - LDS 38.9 KB -> 4 blocks/CU.
// ---------------------------------------------------------------------------
__global__ __launch_bounds__(256, 4) void attn_kernel(
    const bf16* __restrict__ qkv, const int* __restrict__ mask,
    bf16* __restrict__ O)
{
    __shared__ __align__(16) bf16 Ks[2][64 * 64];   // 2 x 8 KB, xor-swizzled
    __shared__ __align__(16) bf16 Vt[64 * 72];      // 9 KB [d][key], stride 72
    __shared__ __align__(16) bf16 Ps[4][16 * 72];   // 9 KB per-wave P
    __shared__ __align__(16) bf16 maskb[2048];      // 4 KB indicator (1/0)

    const int t    = threadIdx.x;
    const int lane = t & 63;
    const int wave = t >> 6;
    const int l15  = lane & 15;
    const int g    = lane >> 4;

    const int bid = blockIdx.x;       // 0..2047
    const int qt  = bid & 31;
    const int bh  = bid >> 5;
    const int h   = bh & 15;
    const int b   = bh >> 4;
    const int q0  = qt * 64 + wave * 16;

    const int* mrow = mask + b * 2048;
    for (int i = t; i < 2048; i += 256)
        maskb[i] = mrow[i] ? (bf16)1.0f : (bf16)0.0f;

    const size_t RS = 3072;
    const bf16* qptr = qkv + (size_t)(b * 2048 + q0 + l15) * RS + h * 64 + g * 8;
    const bf16x8 aQ0 = *(const bf16x8*)(qptr);
    const bf16x8 aQ1 = *(const bf16x8*)(qptr + 32);

    const bf16* kbase = qkv + (size_t)(b * 2048) * RS + 1024 + h * 64;
    const bf16* vbase = qkv + (size_t)(b * 2048) * RS + 2048 + h * 64;

    const f32x4 z = {0.f, 0.f, 0.f, 0.f};
    f32x4 o0 = z, o1 = z, o2 = z, o3 = z, lacc = z;

    // --- staging geometry ---
    // K: thread t covers key kt_= t>>2 (0..63), d-seg (t&3)*16 (2 x b128)
    const int kkey = t >> 2;
    const int kc4  = t & 3;
    const bf16* kp_t = kbase + (size_t)kkey * RS + kc4 * 16;
    const int kd0 = ((2 * kc4)     ^ (kkey & 7)) * 8;   // swizzled dblk slots
    const int kd1 = ((2 * kc4 + 1) ^ (kkey & 7)) * 8;
    // V: thread t covers key t&63, d-range (t>>6)*16..+15
    const int vrow = t & 63;
    const int vd   = (t >> 6) * 16;
    const bf16* vp_t = vbase + (size_t)vrow * RS + vd;

    // QK read swizzle (per-lane, loop-invariant)
    const int rb0 = (g       ^ (l15 & 7)) * 8;
    const int rb1 = ((4 + g) ^ (l15 & 7)) * 8;

    const float SC = 0.72134752f;     // 0.5 * log2(e)

    // ---- prologue: stage chunk 0 ----
    union V16 { uint4 u[2]; bf16 h[16]; };
    V16 cv;
    {
        uint4 k0 = *(const uint4*)(kp_t);
        uint4 k1 = *(const uint4*)(kp_t + 8);
        cv.u[0] = *(const uint4*)(vp_t);
        cv.u[1] = *(const uint4*)(vp_t + 8);
        unsigned vm = mrow[vrow] ? 0xFFFFFFFFu : 0u;
        cv.u[0].x &= vm; cv.u[0].y &= vm; cv.u[0].z &= vm; cv.u[0].w &= vm;
        cv.u[1].x &= vm; cv.u[1].y &= vm; cv.u[1].z &= vm; cv.u[1].w &= vm;
        *(uint4*)(&Ks[0][kkey * 64 + kd0]) = k0;
        *(uint4*)(&Ks[0][kkey * 64 + kd1]) = k1;
    }

    for (int i = 0; i < 32; ++i) {
        const int kc  = i * 64;
        const int buf = i & 1;
        const bool more = (i + 1 < 32);

        __syncthreads();   // A: prev reads done; Ks[buf] writes visible
        // ---- commit V(i) transpose from registers ----
#pragma unroll
        for (int j = 0; j < 16; ++j) Vt[(vd + j) * 72 + vrow] = cv.h[j];
        __syncthreads();   // B: Vt + Ks[buf] ready

        // ---- issue global prefetch for chunk i+1 (consumed at tail) ----
        uint4 nk0, nk1;  V16 nv;  unsigned vm = 0;
        if (more) {
            const bf16* kp = kp_t + (size_t)(kc + 64) * RS;
            const bf16* vp = vp_t + (size_t)(kc + 64) * RS;
            nk0 = *(const uint4*)(kp);
            nk1 = *(const uint4*)(kp + 8);
            nv.u[0] = *(const uint4*)(vp);
            nv.u[1] = *(const uint4*)(vp + 8);
            vm = mrow[kc + 64 + vrow] ? 0xFFFFFFFFu : 0u;
        }
        // ---- denominator mask fragments (LDS broadcast) ----
        const bf16x8 mf0 = *(const bf16x8*)(&maskb[kc + g * 8]);
        const bf16x8 mf1 = *(const bf16x8*)(&maskb[kc + 32 + g * 8]);

        // ---- S = 0.5 * Q K^T  (16 q x 64 keys) from LDS ----
        f32x4 S[4];
#pragma unroll
        for (int kt = 0; kt < 4; ++kt) {
            const bf16* kr = &Ks[buf][(kt * 16 + l15) * 64];
            bf16x8 bk0 = *(const bf16x8*)(kr + rb0);
            bf16x8 bk1 = *(const bf16x8*)(kr + rb1);
            S[kt] = MFMA16(aQ0, bk0, z);
            S[kt] = MFMA16(aQ1, bk1, S[kt]);
        }

        // ---- P = exp2(S*SC)  (mask handled via mf / zeroed V) ----
#pragma unroll
        for (int kt = 0; kt < 4; ++kt) {
#pragma unroll
            for (int r = 0; r < 4; ++r) {
                Ps[wave][(g * 4 + r) * 72 + kt * 16 + l15] =
                    (bf16)__builtin_amdgcn_exp2f(S[kt][r] * SC);
            }
        }
        asm volatile("s_waitcnt lgkmcnt(0)" ::: "memory");  // wave-local fence

        const bf16x8 aP0 = *(const bf16x8*)(&Ps[wave][l15 * 72 + g * 8]);
        const bf16x8 aP1 = *(const bf16x8*)(&Ps[wave][l15 * 72 + 32 + g * 8]);

        lacc = MFMA16(aP0, mf0, lacc);
        lacc = MFMA16(aP1, mf1, lacc);

#pragma unroll
        for (int dt = 0; dt < 4; ++dt) {
            bf16x8 bv0 = *(const bf16x8*)(&Vt[(dt * 16 + l15) * 72 + g * 8]);
            bf16x8 bv1 = *(const bf16x8*)(&Vt[(dt * 16 + l15) * 72 + 32 + g * 8]);
            f32x4* op = (dt == 0) ? &o0 : (dt == 1) ? &o1 : (dt == 2) ? &o2 : &o3;
            *op = MFMA16(aP0, bv0, *op);
            *op = MFMA16(aP1, bv1, *op);
        }

        // ---- tail: commit K(i+1) to other buffer; save masked V(i+1) ----
        if (more) {
            *(uint4*)(&Ks[buf ^ 1][kkey * 64 + kd0]) = nk0;
            *(uint4*)(&Ks[buf ^ 1][kkey * 64 + kd1]) = nk1;
            nv.u[0].x &= vm; nv.u[0].y &= vm; nv.u[0].z &= vm; nv.u[0].w &= vm;
            nv.u[1].x &= vm; nv.u[1].y &= vm; nv.u[1].z &= vm; nv.u[1].w &= vm;
            cv = nv;
        }
    }

    // ---- normalize + store ----
    float inv[4];
#pragma unroll
    for (int r = 0; r < 4; ++r) inv[r] = 1.0f / fmaxf(lacc[r], 1e-30f);

    const f32x4 oo[4] = {o0, o1, o2, o3};
#pragma unroll
    for (int nt = 0; nt < 4; ++nt) {
#pragma unroll
        for (int r = 0; r < 4; ++r) {
            int row = q0 + g * 4 + r;
            int d   = nt * 16 + l15;
            O[(size_t)(b * 2048 + row) * 1024 + h * 64 + d] = (bf16)(oo[nt][r] * inv[r]);
        }
    }
}

// ---------------------------------------------------------------------------
extern "C" void kernel_launch(void* const* d_in, const int* in_sizes, int n_in,
                              void* d_out, int out_size, void* d_ws, size_t ws_size,
                              hipStream_t stream)
{
    const float* x     = (const float*)d_in[0];
    const int*   mask  = (const int*)d_in[1];
    const float* w_qkv = (const float*)d_in[2];
    const float* b_qkv = (const float*)d_in[3];
    const float* w_out = (const float*)d_in[4];
    const float* b_out = (const float*)d_in[5];
    float* out = (float*)d_out;

    char* ws = (char*)d_ws;
    bf16* qkvb  = (bf16*)(ws);                 // 48 MiB: [8192][3072]
    bf16* Obuf  = (bf16*)(ws + 50331648);      // 16 MiB: [8192][1024]
    bf16* xb    = (bf16*)(ws + 67108864);      // 16 MiB: [8192][1024]
    bf16* wqkvT = (bf16*)(ws + 83886080);      //  6 MiB: [3072][1024]
    bf16* woutT = (bf16*)(ws + 90177536);      //  2 MiB: [1024][1024]

    cvt_f32_bf16<<<dim3(8192), 256, 0, stream>>>(x, xb, 2097152);
    transpose_f32_bf16<<<dim3(48, 16), 256, 0, stream>>>(w_qkv, wqkvT, 1024, 3072);
    transpose_f32_bf16<<<dim3(16, 16), 256, 0, stream>>>(w_out, woutT, 1024, 1024);
    gemm_bias_kernel<bf16><<<dim3(24, 64), 256, 0, stream>>>(xb, wqkvT, b_qkv, qkvb, 8192, 3072, 1024);
    attn_kernel<<<dim3(2048), 256, 0, stream>>>(qkvb, mask, Obuf);
    gemm_bias_kernel<float><<<dim3(8, 64), 256, 0, stream>>>(Obuf, woutT, b_out, out, 8192, 1024, 1024);
}

// Round 6
// 335.230 us; speedup vs baseline: 1.7154x; 1.0309x over previous
//
#include <hip/hip_runtime.h>

// ---------------------------------------------------------------------------
// AttentionMulti: x[4,2048,1024] fp32 -> qkv -> 16-head attention (D=64,
// scale=0.5, key-mask) -> out proj.  Inputs/outputs fp32, mask int32.
// Internal compute in bf16 MFMA.
// ---------------------------------------------------------------------------

typedef __bf16 bf16;
typedef __attribute__((ext_vector_type(8))) __bf16 bf16x8;
typedef __attribute__((ext_vector_type(4))) float f32x4;

#define MFMA16(a, b, c) __builtin_amdgcn_mfma_f32_16x16x32_bf16(a, b, c, 0, 0, 0)

// ---------------------------------------------------------------------------
__global__ __launch_bounds__(256, 1) void cvt_f32_bf16(
    const float* __restrict__ in, bf16* __restrict__ out, int n4)
{
    int i = blockIdx.x * 256 + threadIdx.x;
    if (i >= n4) return;
    float4 v = *(const float4*)(in + (size_t)i * 4);
    union { ushort4 u; bf16 h[4]; } o;
    o.h[0] = (bf16)v.x; o.h[1] = (bf16)v.y; o.h[2] = (bf16)v.z; o.h[3] = (bf16)v.w;
    *(ushort4*)(out + (size_t)i * 4) = o.u;
}

// ---------------------------------------------------------------------------
__global__ __launch_bounds__(256, 1) void transpose_f32_bf16(
    const float* __restrict__ in, bf16* __restrict__ out, int R, int C)
{
    __shared__ float s[64][65];
    const int t  = threadIdx.x;
    const int r0 = blockIdx.y * 64;
    const int c0 = blockIdx.x * 64;
    const int tr  = t >> 4;
    const int tc4 = (t & 15) * 4;
#pragma unroll
    for (int p = 0; p < 4; ++p) {
        int r = tr + p * 16;
        float4 v = *(const float4*)(in + (size_t)(r0 + r) * C + c0 + tc4);
        s[r][tc4 + 0] = v.x; s[r][tc4 + 1] = v.y;
        s[r][tc4 + 2] = v.z; s[r][tc4 + 3] = v.w;
    }
    __syncthreads();
    const int cw  = t >> 3;
    const int rw8 = (t & 7) * 8;
#pragma unroll
    for (int p = 0; p < 2; ++p) {
        int c = cw + p * 32;
        union { uint4 v; bf16 h[8]; } u;
#pragma unroll
        for (int j = 0; j < 8; ++j) u.h[j] = (bf16)s[rw8 + j][c];
        *(uint4*)(out + (size_t)(c0 + c) * R + r0 + rw8) = u.v;
    }
}

// ---------------------------------------------------------------------------
// C[M][N] = A[M][K] @ Bt[N][K]^T + bias[N]   (m97-style 128x128 tile, BK=32)
// ---------------------------------------------------------------------------
template <typename OutT>
__global__ __launch_bounds__(256, 1) void gemm_bias_kernel(
    const bf16* __restrict__ A, const bf16* __restrict__ Bt,
    const float* __restrict__ bias, OutT* __restrict__ C,
    int M, int N, int K)
{
    __shared__ __align__(16) bf16 As[128 * 32];
    __shared__ __align__(16) bf16 Bs[128 * 32];
    const int t    = threadIdx.x;
    const int lane = t & 63;
    const int wave = t >> 6;
    const int l15  = lane & 15;
    const int g    = lane >> 4;
    const int m0   = blockIdx.y * 128;
    const int n0   = blockIdx.x * 128;
    const int wr   = (wave >> 1) * 64;
    const int wc   = (wave & 1) * 64;

    const f32x4 z = {0.f, 0.f, 0.f, 0.f};
    f32x4 acc[4][4];
#pragma unroll
    for (int i = 0; i < 4; ++i)
#pragma unroll
        for (int j = 0; j < 4; ++j) acc[i][j] = z;

    const int e0 = t * 8;

    for (int k0 = 0; k0 < K; k0 += 32) {
        __syncthreads();
#pragma unroll
        for (int rnd = 0; rnd < 2; ++rnd) {
            int e   = e0 + rnd * 2048;
            int row = e >> 5;
            int col = e & 31;
            __builtin_amdgcn_global_load_lds(
                (const __attribute__((address_space(1))) void*)(A + (size_t)(m0 + row) * K + k0 + col),
                (__attribute__((address_space(3))) void*)(As + e), 16, 0, 0);
            __builtin_amdgcn_global_load_lds(
                (const __attribute__((address_space(1))) void*)(Bt + (size_t)(n0 + row) * K + k0 + col),
                (__attribute__((address_space(3))) void*)(Bs + e), 16, 0, 0);
        }
        asm volatile("s_waitcnt vmcnt(0)" ::: "memory");
        __syncthreads();

        bf16x8 a[4], b[4];
#pragma unroll
        for (int i = 0; i < 4; ++i)
            a[i] = *(const bf16x8*)(As + (wr + i * 16 + l15) * 32 + g * 8);
#pragma unroll
        for (int j = 0; j < 4; ++j)
            b[j] = *(const bf16x8*)(Bs + (wc + j * 16 + l15) * 32 + g * 8);
#pragma unroll
        for (int i = 0; i < 4; ++i)
#pragma unroll
            for (int j = 0; j < 4; ++j)
                acc[i][j] = MFMA16(a[i], b[j], acc[i][j]);
    }

#pragma unroll
    for (int i = 0; i < 4; ++i) {
#pragma unroll
        for (int j = 0; j < 4; ++j) {
#pragma unroll
            for (int r = 0; r < 4; ++r) {
                int row = m0 + wr + i * 16 + g * 4 + r;
                int col = n0 + wc + j * 16 + l15;
                float v = acc[i][j][r] + bias[col];
                C[(size_t)row * N + col] = (OutT)v;
            }
        }
    }
}

// ---------------------------------------------------------------------------
// Attention v4:
//  - 128 q-rows per block (each wave: two 16-row q-tiles sharing K frags)
//    -> 1024 blocks; per-q K/V staging cost halved (LDS-BW was the floor).
//  - Ks AND Vt double-buffered -> ONE __syncthreads per 64-key chunk.
//  - Ps/Vt row stride 80 (160 B): b16 scatter writes hit all 32 banks
//    (stride-72 Ps writes were the measured 1.05e7 conflict source).
//  - Global K/V prefetch in regs across the body; mask via zeroed V rows +
//    indicator-fragment denominator MFMA.
//  - LDS 50 KB -> 3 blocks/CU; bv streamed at use-point to hold VGPR < 170.
// ---------------------------------------------------------------------------
__global__ __launch_bounds__(256, 3) void attn_kernel(
    const bf16* __restrict__ qkv, const int* __restrict__ mask,
    bf16* __restrict__ O)
{
    __shared__ __align__(16) bf16 Ks[2][64 * 64];   // 16 KB, xor-swizzled
    __shared__ __align__(16) bf16 Vt[2][64 * 80];   // 20 KB [d][key]
    __shared__ __align__(16) bf16 Ps[4][16 * 80];   // 10 KB per-wave P
    __shared__ __align__(16) bf16 maskb[2048];      //  4 KB indicator (1/0)

    const int t    = threadIdx.x;
    const int lane = t & 63;
    const int wave = t >> 6;
    const int l15  = lane & 15;
    const int g    = lane >> 4;

    const int bid = blockIdx.x;       // 0..1023
    const int qt  = bid & 15;         // 128-row q-tile
    const int bh  = bid >> 4;
    const int h   = bh & 15;
    const int b   = bh >> 4;
    const int q0  = qt * 128 + wave * 16;   // tile0; tile1 = q0 + 64

    const int* mrow = mask + b * 2048;
    for (int i = t; i < 2048; i += 256)
        maskb[i] = mrow[i] ? (bf16)1.0f : (bf16)0.0f;

    const size_t RS = 3072;
    const bf16* qp0 = qkv + (size_t)(b * 2048 + q0 + l15) * RS + h * 64 + g * 8;
    const bf16* qp1 = qp0 + (size_t)64 * RS;
    bf16x8 aQ[2][2];
    aQ[0][0] = *(const bf16x8*)(qp0);
    aQ[0][1] = *(const bf16x8*)(qp0 + 32);
    aQ[1][0] = *(const bf16x8*)(qp1);
    aQ[1][1] = *(const bf16x8*)(qp1 + 32);

    const bf16* kbase = qkv + (size_t)(b * 2048) * RS + 1024 + h * 64;
    const bf16* vbase = qkv + (size_t)(b * 2048) * RS + 2048 + h * 64;

    const f32x4 z = {0.f, 0.f, 0.f, 0.f};
    f32x4 o0[4] = {z, z, z, z}, o1[4] = {z, z, z, z};
    f32x4 lacc0 = z, lacc1 = z;

    // --- staging geometry ---
    const int kkey = t >> 2;                    // K: key 0..63
    const int kc4  = t & 3;                     //    d-seg (2 x b128)
    const bf16* kp_t = kbase + (size_t)kkey * RS + kc4 * 16;
    const int kd0 = ((2 * kc4)     ^ (kkey & 7)) * 8;
    const int kd1 = ((2 * kc4 + 1) ^ (kkey & 7)) * 8;
    const int vrow = t & 63;                    // V: key
    const int vd   = (t >> 6) * 16;             //    d-range
    const bf16* vp_t = vbase + (size_t)vrow * RS + vd;

    const int rb0 = (g       ^ (l15 & 7)) * 8;  // QK read swizzle
    const int rb1 = ((4 + g) ^ (l15 & 7)) * 8;

    const float SC = 0.72134752f;               // 0.5 * log2(e)

    union V16 { uint4 u[2]; bf16 h[16]; };

    // ---- prologue: stage chunk 0 into buffers[0] ----
    {
        uint4 k0 = *(const uint4*)(kp_t);
        uint4 k1 = *(const uint4*)(kp_t + 8);
        V16 v;
        v.u[0] = *(const uint4*)(vp_t);
        v.u[1] = *(const uint4*)(vp_t + 8);
        unsigned vm = mrow[vrow] ? 0xFFFFFFFFu : 0u;
        v.u[0].x &= vm; v.u[0].y &= vm; v.u[0].z &= vm; v.u[0].w &= vm;
        v.u[1].x &= vm; v.u[1].y &= vm; v.u[1].z &= vm; v.u[1].w &= vm;
        *(uint4*)(&Ks[0][kkey * 64 + kd0]) = k0;
        *(uint4*)(&Ks[0][kkey * 64 + kd1]) = k1;
#pragma unroll
        for (int j = 0; j < 16; ++j) Vt[0][(vd + j) * 80 + vrow] = v.h[j];
    }
    __syncthreads();

    for (int i = 0; i < 32; ++i) {
        const int kc  = i * 64;
        const int buf = i & 1;
        const bool more = (i + 1 < 32);

        // ---- issue global prefetch for chunk i+1 (consumed at tail) ----
        uint4 nk0, nk1;  V16 nv;  unsigned vm = 0;
        if (more) {
            const bf16* kp = kp_t + (size_t)(kc + 64) * RS;
            const bf16* vp = vp_t + (size_t)(kc + 64) * RS;
            nk0 = *(const uint4*)(kp);
            nk1 = *(const uint4*)(kp + 8);
            nv.u[0] = *(const uint4*)(vp);
            nv.u[1] = *(const uint4*)(vp + 8);
            vm = mrow[kc + 64 + vrow] ? 0xFFFFFFFFu : 0u;
        }

        const bf16x8 mf0 = *(const bf16x8*)(&maskb[kc + g * 8]);
        const bf16x8 mf1 = *(const bf16x8*)(&maskb[kc + 32 + g * 8]);

        // ---- K fragments, shared by both q-tiles ----
        bf16x8 bk[4][2];
#pragma unroll
        for (int kt = 0; kt < 4; ++kt) {
            const bf16* kr = &Ks[buf][(kt * 16 + l15) * 64];
            bk[kt][0] = *(const bf16x8*)(kr + rb0);
            bk[kt][1] = *(const bf16x8*)(kr + rb1);
        }

        // ---- tile 0: S, exp, P roundtrip ----
        f32x4 S[4];
#pragma unroll
        for (int kt = 0; kt < 4; ++kt) {
            S[kt] = MFMA16(aQ[0][0], bk[kt][0], z);
            S[kt] = MFMA16(aQ[0][1], bk[kt][1], S[kt]);
        }
#pragma unroll
        for (int kt = 0; kt < 4; ++kt)
#pragma unroll
            for (int r = 0; r < 4; ++r)
                Ps[wave][(g * 4 + r) * 80 + kt * 16 + l15] =
                    (bf16)__builtin_amdgcn_exp2f(S[kt][r] * SC);
        asm volatile("s_waitcnt lgkmcnt(0)" ::: "memory");
        const bf16x8 aP00 = *(const bf16x8*)(&Ps[wave][l15 * 80 + g * 8]);
        const bf16x8 aP01 = *(const bf16x8*)(&Ps[wave][l15 * 80 + 32 + g * 8]);
        asm volatile("s_waitcnt lgkmcnt(0)" ::: "memory");  // aP0 in regs; Ps reusable

        // ---- tile 1: S (reusing bk), exp, write P ----
#pragma unroll
        for (int kt = 0; kt < 4; ++kt) {
            S[kt] = MFMA16(aQ[1][0], bk[kt][0], z);
            S[kt] = MFMA16(aQ[1][1], bk[kt][1], S[kt]);
        }
#pragma unroll
        for (int kt = 0; kt < 4; ++kt)
#pragma unroll
            for (int r = 0; r < 4; ++r)
                Ps[wave][(g * 4 + r) * 80 + kt * 16 + l15] =
                    (bf16)__builtin_amdgcn_exp2f(S[kt][r] * SC);

        // ---- tile 0 accumulate (overlaps tile-1 roundtrip latency) ----
        lacc0 = MFMA16(aP00, mf0, lacc0);
        lacc0 = MFMA16(aP01, mf1, lacc0);
#pragma unroll
        for (int dt = 0; dt < 4; ++dt) {
            bf16x8 bv0 = *(const bf16x8*)(&Vt[buf][(dt * 16 + l15) * 80 + g * 8]);
            bf16x8 bv1 = *(const bf16x8*)(&Vt[buf][(dt * 16 + l15) * 80 + 32 + g * 8]);
            o0[dt] = MFMA16(aP00, bv0, o0[dt]);
            o0[dt] = MFMA16(aP01, bv1, o0[dt]);
        }
        asm volatile("s_waitcnt lgkmcnt(0)" ::: "memory");  // P1 committed
        const bf16x8 aP10 = *(const bf16x8*)(&Ps[wave][l15 * 80 + g * 8]);
        const bf16x8 aP11 = *(const bf16x8*)(&Ps[wave][l15 * 80 + 32 + g * 8]);

        // ---- tile 1 accumulate ----
        lacc1 = MFMA16(aP10, mf0, lacc1);
        lacc1 = MFMA16(aP11, mf1, lacc1);
#pragma unroll
        for (int dt = 0; dt < 4; ++dt) {
            bf16x8 bv0 = *(const bf16x8*)(&Vt[buf][(dt * 16 + l15) * 80 + g * 8]);
            bf16x8 bv1 = *(const bf16x8*)(&Vt[buf][(dt * 16 + l15) * 80 + 32 + g * 8]);
            o1[dt] = MFMA16(aP10, bv0, o1[dt]);
            o1[dt] = MFMA16(aP11, bv1, o1[dt]);
        }

        // ---- tail: commit chunk i+1 into the other buffers ----
        if (more) {
            *(uint4*)(&Ks[buf ^ 1][kkey * 64 + kd0]) = nk0;
            *(uint4*)(&Ks[buf ^ 1][kkey * 64 + kd1]) = nk1;
            nv.u[0].x &= vm; nv.u[0].y &= vm; nv.u[0].z &= vm; nv.u[0].w &= vm;
            nv.u[1].x &= vm; nv.u[1].y &= vm; nv.u[1].z &= vm; nv.u[1].w &= vm;
#pragma unroll
            for (int j = 0; j < 16; ++j) Vt[buf ^ 1][(vd + j) * 80 + vrow] = nv.h[j];
        }
        __syncthreads();   // single barrier: buf^1 published, buf reads done
    }

    // ---- normalize + store both tiles ----
    float inv0[4], inv1[4];
#pragma unroll
    for (int r = 0; r < 4; ++r) {
        inv0[r] = 1.0f / fmaxf(lacc0[r], 1e-30f);
        inv1[r] = 1.0f / fmaxf(lacc1[r], 1e-30f);
    }
#pragma unroll
    for (int nt = 0; nt < 4; ++nt) {
#pragma unroll
        for (int r = 0; r < 4; ++r) {
            int d = nt * 16 + l15;
            int row0 = q0 + g * 4 + r;
            O[(size_t)(b * 2048 + row0) * 1024 + h * 64 + d] = (bf16)(o0[nt][r] * inv0[r]);
            O[(size_t)(b * 2048 + row0 + 64) * 1024 + h * 64 + d] = (bf16)(o1[nt][r] * inv1[r]);
        }
    }
}

// ---------------------------------------------------------------------------
extern "C" void kernel_launch(void* const* d_in, const int* in_sizes, int n_in,
                              void* d_out, int out_size, void* d_ws, size_t ws_size,
                              hipStream_t stream)
{
    const float* x     = (const float*)d_in[0];
    const int*   mask  = (const int*)d_in[1];
    const float* w_qkv = (const float*)d_in[2];
    const float* b_qkv = (const float*)d_in[3];
    const float* w_out = (const float*)d_in[4];
    const float* b_out = (const float*)d_in[5];
    float* out = (float*)d_out;

    char* ws = (char*)d_ws;
    bf16* qkvb  = (bf16*)(ws);                 // 48 MiB: [8192][3072]
    bf16* Obuf  = (bf16*)(ws + 50331648);      // 16 MiB: [8192][1024]
    bf16* xb    = (bf16*)(ws + 67108864);      // 16 MiB: [8192][1024]
    bf16* wqkvT = (bf16*)(ws + 83886080);      //  6 MiB: [3072][1024]
    bf16* woutT = (bf16*)(ws + 90177536);      //  2 MiB: [1024][1024]

    cvt_f32_bf16<<<dim3(8192), 256, 0, stream>>>(x, xb, 2097152);
    transpose_f32_bf16<<<dim3(48, 16), 256, 0, stream>>>(w_qkv, wqkvT, 1024, 3072);
    transpose_f32_bf16<<<dim3(16, 16), 256, 0, stream>>>(w_out, woutT, 1024, 1024);
    gemm_bias_kernel<bf16><<<dim3(24, 64), 256, 0, stream>>>(xb, wqkvT, b_qkv, qkvb, 8192, 3072, 1024);
    attn_kernel<<<dim3(1024), 256, 0, stream>>>(qkvb, mask, Obuf);
    gemm_bias_kernel<float><<<dim3(8, 64), 256, 0, stream>>>(Obuf, woutT, b_out, out, 8192, 1024, 1024);
}